// Round 8
// baseline (3053.874 us; speedup 1.0000x reference)
//
#include <hip/hip_runtime.h>

typedef float f32x4 __attribute__((ext_vector_type(4)));
typedef short bf16x8 __attribute__((ext_vector_type(8)));

#define TT    2048
#define DDIM  128
#define G3    384
#define NBBLK 16
#define GXROW 6144   /* ushorts per t per batch-block */
#define GX_BYTES ((size_t)NBBLK * TT * GXROW * 2)  /* 402,653,184 B */

#define SCL_ZR (-1.4426950408889634f)
#define SCL_N  (-2.8853900817779268f)

__device__ __forceinline__ unsigned f2bf_u(float f) {
    unsigned u = __float_as_uint(f);
    return (u + 0x7FFFu + ((u >> 16) & 1u)) >> 16;   // RNE f32->bf16
}
__device__ __forceinline__ float bf_lo(unsigned u) { return __uint_as_float(u << 16); }
__device__ __forceinline__ float bf_hi(unsigned u) { return __uint_as_float(u & 0xffff0000u); }
__device__ __forceinline__ float rcp_(float x) { return __builtin_amdgcn_rcpf(x); }
__device__ __forceinline__ float exp2_(float x) {
    float d;
    asm("v_exp_f32 %0, %1" : "=v"(d) : "v"(x));   // register-only, safe
    return d;
}
__device__ __forceinline__ float sigm_(float v) { return rcp_(1.0f + exp2_(-1.4426950408889634f * v)); }
__device__ __forceinline__ float tanhf_(float v) { return 2.0f * rcp_(1.0f + exp2_(-2.8853900817779268f * v)) - 1.0f; }
__device__ __forceinline__ unsigned cvt_pk_bf16(float lo, float hi) {
    unsigned d;
    asm("v_cvt_pk_bf16_f32 %0, %1, %2" : "=v"(d) : "v"(lo), "v"(hi));
    return d;
}

// ---------------------------------------------------------------------------
// Kernel 1: gx^T = (x_t @ W + b)^T via swapped-operand MFMA. Unchanged layout:
// gx (ushort): [bblk][t][tile(24: 8z,8r,8n)][lk(4)][lc(16)][4], pre-scaled.
// ---------------------------------------------------------------------------
__global__ __launch_bounds__(256) void gx_gemm(
    const float* __restrict__ x, const float* __restrict__ W,
    const float* __restrict__ bias, unsigned short* __restrict__ gx)
{
    const int bblk  = blockIdx.x;
    const int ttile = blockIdx.y;
    const int tid = threadIdx.x;
    const int w  = tid >> 6;
    const int l  = tid & 63;
    const int lc = l & 15;
    const int lk = l >> 4;

    __shared__ unsigned short xs[16 * 16 * DDIM];   // [t16][r16][d128] bf16, swizzled

    const int tiles[6] = {2*w, 2*w+1, 2*w+8, 2*w+9, 2*w+16, 2*w+17};

    bf16x8 wfrag[6][4];
    f32x4  binit[6];
    #pragma unroll
    for (int i6 = 0; i6 < 6; ++i6) {
        const float scl = (i6 >= 4) ? SCL_N : SCL_ZR;
        #pragma unroll
        for (int i = 0; i < 4; ++i)
            binit[i6][i] = bias[tiles[i6] * 16 + lk * 4 + i] * scl;
        #pragma unroll
        for (int kt = 0; kt < 4; ++kt) {
            bf16x8 f;
            #pragma unroll
            for (int jj = 0; jj < 8; ++jj) {
                const int k = kt * 32 + lk * 8 + jj;
                f[jj] = (short)f2bf_u(W[k * G3 + tiles[i6] * 16 + lc] * scl);
            }
            wfrag[i6][kt] = f;
        }
    }

    int inoff[4];
    #pragma unroll
    for (int kt = 0; kt < 4; ++kt)
        inoff[kt] = (lc * 256 + kt * 64 + lk * 16) ^ ((lc & 7) << 4);

    const float* xb = x + (size_t)bblk * 16 * DDIM * TT;
    const int t0blk = ttile * 128;
    const int tq = tid & 3;
    const int pbase = tid >> 2;

    for (int chunk = 0; chunk < 8; ++chunk) {
        __syncthreads();
        const int t0 = t0blk + chunk * 16 + tq * 4;
        #pragma unroll 4
        for (int pp = 0; pp < 32; ++pp) {
            const int p = pbase + pp * 64;
            const int r = p >> 7, d = p & 127;
            f32x4 v = *(const f32x4*)(xb + (size_t)p * TT + t0);
            char* bp = (char*)xs + (tq * 4) * 4096 + (((r * 128 + d) * 2) ^ ((r & 7) << 4));
            const unsigned pkA = cvt_pk_bf16(v[0], v[1]);
            const unsigned pkB = cvt_pk_bf16(v[2], v[3]);
            *(unsigned short*)(bp)         = (unsigned short)pkA;
            *(unsigned short*)(bp + 4096)  = (unsigned short)(pkA >> 16);
            *(unsigned short*)(bp + 8192)  = (unsigned short)pkB;
            *(unsigned short*)(bp + 12288) = (unsigned short)(pkB >> 16);
        }
        __syncthreads();

        for (int t = 0; t < 16; ++t) {
            bf16x8 a[4];
            #pragma unroll
            for (int kt = 0; kt < 4; ++kt)
                a[kt] = *(const bf16x8*)((const char*)xs + t * 4096 + inoff[kt]);

            const int tglob = t0blk + chunk * 16 + t;
            #pragma unroll
            for (int i6 = 0; i6 < 6; ++i6) {
                f32x4 acc = binit[i6];
                #pragma unroll
                for (int kt = 0; kt < 4; ++kt)
                    acc = __builtin_amdgcn_mfma_f32_16x16x32_bf16(wfrag[i6][kt], a[kt], acc, 0, 0, 0);
                unsigned p0 = cvt_pk_bf16(acc[0], acc[1]);
                unsigned p1 = cvt_pk_bf16(acc[2], acc[3]);
                const size_t off = (size_t)(bblk * TT + tglob) * GXROW
                                   + (size_t)(((tiles[i6] * 4 + lk) * 16 + lc) * 4);
                *(uint2*)(gx + off) = make_uint2(p0, p1);
            }
        }
    }
}

// ---------------------------------------------------------------------------
// Kernel 2: sequential GRU recurrence — TWO independent batch-blocks per
// 1024-thread block (waves 0-7 -> bblk even, 8-15 -> bblk odd) so each SIMD
// hosts 4 waves from 2 independent chains (latency of one hides under the
// other). Per half: 8KB h-dbuf + 64KB f32 out staging (8 steps). hlds store
// moved AFTER the barrier (off the lgkm critical path).
// ---------------------------------------------------------------------------
__global__ __launch_bounds__(1024) void gru_rec(
    const unsigned short* __restrict__ gx, const float* __restrict__ U,
    float* __restrict__ out)
{
    const int tid  = threadIdx.x;
    const int half = tid >> 9;
    const int t2   = tid & 511;
    const int w  = t2 >> 6;
    const int l  = t2 & 63;
    const int lc = l & 15, lk = l >> 4;
    const int bblk = blockIdx.x * 2 + half;

    // A-operand: U^T fragments, pre-scaled
    bf16x8 uz[4], ur[4], un[4];
    #pragma unroll
    for (int kt = 0; kt < 4; ++kt) {
        bf16x8 fz, fr, fn;
        #pragma unroll
        for (int jj = 0; jj < 8; ++jj) {
            const int k = kt * 32 + lk * 8 + jj;
            fz[jj] = (short)f2bf_u(U[k * G3 + (w * 16 + lc)] * SCL_ZR);
            fr[jj] = (short)f2bf_u(U[k * G3 + 128 + (w * 16 + lc)] * SCL_ZR);
            fn[jj] = (short)f2bf_u(U[k * G3 + 256 + (w * 16 + lc)] * SCL_N);
        }
        uz[kt] = fz; ur[kt] = fr; un[kt] = fn;
    }

    __shared__ unsigned short hsA[2][2 * 2048];   // per-half: 2 bufs x [b16][d128] bf16
    __shared__ float hlds[2][8 * 16 * 128];       // per-half: [t8][b16][d128] f32, swizzled
    #pragma unroll
    for (int i = t2; i < 4096; i += 512) hsA[half][i] = 0;
    char* const hsA_h  = (char*)&hsA[half][0];
    char* const hb_lds = (char*)&hlds[half][0];

    // B-frag (h) read byte-offsets
    int roff[4];
    #pragma unroll
    for (int kt = 0; kt < 4; ++kt)
        roff[kt] = lc * 256 + ((kt * 64 + lk * 16) ^ (lc << 4));

    // h write: single b64 at row lc, d-cols w*16+lk*4..+3
    const int wb64 = lc * 256 + ((w * 32 + lk * 8) ^ (lc << 4));

    // hlds write: addr = hlv[J>>2] + (J&3)*8192
    int hlv[2];
    {
        const int base = lc * 512 + ((w * 64 + lk * 16) ^ ((lc & 7) << 4));
        hlv[0] = base;
        hlv[1] = 32768 + (base ^ (1 << 6));
    }

    // flush: lane covers (d=dl, t-quad q, batch-half bh); round r: b = r + 8*bh
    const int dl  = w * 16 + (l >> 2);
    const int bh  = (l & 3) >> 1;
    const int q   = l & 1;
    const int flA = ((dl * 4) ^ (q << 6)) + q * 32768;
    float* outfl = out + (size_t)(bblk * 16 + 8 * bh) * DDIM * TT + (size_t)dl * TT + q * 16/4*4;
    // (q*4 floats along t)
    float* outq = out + ((size_t)(bblk * 16 + 8 * bh) * DDIM + dl) * TT + q * 4;

    float hold[4] = {0.f, 0.f, 0.f, 0.f};

    const unsigned short* g0 = gx + (size_t)bblk * TT * GXROW
                               + (size_t)(((w * 4 + lk) * 16 + lc) * 4);

    // depth-4 gx prefetch ring
    uint2 rgz[4], rgr[4], rgn[4];
    #pragma unroll
    for (int d = 0; d < 4; ++d) {
        const unsigned short* gq = g0 + (size_t)d * GXROW;
        rgz[d] = *(const uint2*)(gq);
        rgr[d] = *(const uint2*)(gq + 2048);
        rgn[d] = *(const uint2*)(gq + 4096);
    }

    __syncthreads();

#define GATE(I)                                                               \
    {                                                                         \
        const float zz = rcp_(1.0f + exp2_(az_a[I] + az_b[I]));               \
        const float rr = rcp_(1.0f + exp2_(ar_a[I] + ar_b[I]));               \
        const float uu = gn##I + rr * (an_a[I] + an_b[I]);                    \
        const float nn = 2.0f * rcp_(1.0f + exp2_(uu)) - 1.0f;                \
        const float hn = nn + zz * (hold[I] - nn);                            \
        hold[I] = hn;                                                         \
        hh[I] = hn;                                                           \
    }

#define SUBSTEP(J, DOPF)                                                      \
    {                                                                         \
        const char* hb = hsA_h + ((J) & 1) * 4096;                            \
        bf16x8 b0 = *(const bf16x8*)(hb + roff[0]);                           \
        bf16x8 b1 = *(const bf16x8*)(hb + roff[1]);                           \
        bf16x8 b2 = *(const bf16x8*)(hb + roff[2]);                           \
        bf16x8 b3 = *(const bf16x8*)(hb + roff[3]);                           \
        uint2 pz = rgz[(J) & 3], pr = rgr[(J) & 3], pn = rgn[(J) & 3];        \
        if (DOPF) {                                                           \
            const unsigned short* gq = gpt + (size_t)((J) + 4) * GXROW;       \
            rgz[(J) & 3] = *(const uint2*)(gq);                               \
            rgr[(J) & 3] = *(const uint2*)(gq + 2048);                        \
            rgn[(J) & 3] = *(const uint2*)(gq + 4096);                        \
        }                                                                     \
        f32x4 az_a, ar_a;                                                     \
        az_a[0] = bf_lo(pz.x); az_a[1] = bf_hi(pz.x);                         \
        az_a[2] = bf_lo(pz.y); az_a[3] = bf_hi(pz.y);                         \
        ar_a[0] = bf_lo(pr.x); ar_a[1] = bf_hi(pr.x);                         \
        ar_a[2] = bf_lo(pr.y); ar_a[3] = bf_hi(pr.y);                         \
        const float gn0 = bf_lo(pn.x), gn1 = bf_hi(pn.x);                     \
        const float gn2 = bf_lo(pn.y), gn3 = bf_hi(pn.y);                     \
        f32x4 an_a = (f32x4){0.f, 0.f, 0.f, 0.f};                             \
        f32x4 an_b = an_a, az_b = an_a, ar_b = an_a;                          \
        an_a = __builtin_amdgcn_mfma_f32_16x16x32_bf16(un[0], b0, an_a, 0, 0, 0); \
        an_b = __builtin_amdgcn_mfma_f32_16x16x32_bf16(un[2], b2, an_b, 0, 0, 0); \
        az_a = __builtin_amdgcn_mfma_f32_16x16x32_bf16(uz[0], b0, az_a, 0, 0, 0); \
        az_b = __builtin_amdgcn_mfma_f32_16x16x32_bf16(uz[2], b2, az_b, 0, 0, 0); \
        ar_a = __builtin_amdgcn_mfma_f32_16x16x32_bf16(ur[0], b0, ar_a, 0, 0, 0); \
        ar_b = __builtin_amdgcn_mfma_f32_16x16x32_bf16(ur[2], b2, ar_b, 0, 0, 0); \
        an_a = __builtin_amdgcn_mfma_f32_16x16x32_bf16(un[1], b1, an_a, 0, 0, 0); \
        an_b = __builtin_amdgcn_mfma_f32_16x16x32_bf16(un[3], b3, an_b, 0, 0, 0); \
        az_a = __builtin_amdgcn_mfma_f32_16x16x32_bf16(uz[1], b1, az_a, 0, 0, 0); \
        az_b = __builtin_amdgcn_mfma_f32_16x16x32_bf16(uz[3], b3, az_b, 0, 0, 0); \
        ar_a = __builtin_amdgcn_mfma_f32_16x16x32_bf16(ur[1], b1, ar_a, 0, 0, 0); \
        ar_b = __builtin_amdgcn_mfma_f32_16x16x32_bf16(ur[3], b3, ar_b, 0, 0, 0); \
        float hh[4];                                                          \
        GATE(0) GATE(1) GATE(2) GATE(3)                                       \
        {                                                                     \
            const unsigned pk01 = cvt_pk_bf16(hh[0], hh[1]);                  \
            const unsigned pk23 = cvt_pk_bf16(hh[2], hh[3]);                  \
            *(uint2*)(hsA_h + ((((J) & 1) ^ 1) * 4096) + wb64)                \
                = make_uint2(pk01, pk23);                                     \
        }                                                                     \
        asm volatile("s_waitcnt lgkmcnt(0)" ::: "memory");                    \
        __builtin_amdgcn_s_barrier();                                         \
        /* out staging AFTER barrier: off the critical path; drained by the */ \
        /* next substep's lgkmcnt(0) (or FLUSH's explicit wait).            */ \
        *(f32x4*)(hb_lds + hlv[(J) >> 2] + ((J) & 3) * 8192)                  \
            = (f32x4){hh[0], hh[1], hh[2], hh[3]};                            \
    }

    // flush 8 staged steps; own-wave data only (no barrier, just lgkm drain)
#define FLUSH(T0)                                                             \
    asm volatile("s_waitcnt lgkmcnt(0)" ::: "memory");                        \
    _Pragma("unroll")                                                         \
    for (int r = 0; r < 8; ++r) {                                             \
        const int b_ = r + 8 * bh;                                            \
        const int fr = q * 32768 + b_ * 512 + (((dl * 4) ^ ((b_ & 7) << 4)) ^ (q << 6)); \
        f32x4 v;                                                              \
        _Pragma("unroll")                                                     \
        for (int k = 0; k < 4; ++k)                                           \
            v[k] = *(const float*)(hb_lds + fr + k * 8192);                   \
        *(f32x4*)(outq + (size_t)r * (DDIM * TT) + (T0)) = v;                 \
    }

    for (int t = 0; t < TT - 8; t += 8) {
        const unsigned short* gpt = g0 + (size_t)t * GXROW;
        SUBSTEP(0, true) SUBSTEP(1, true) SUBSTEP(2, true) SUBSTEP(3, true)
        SUBSTEP(4, true) SUBSTEP(5, true) SUBSTEP(6, true) SUBSTEP(7, true)
        FLUSH(t)
    }
    {
        const int t = TT - 8;
        const unsigned short* gpt = g0 + (size_t)t * GXROW;
        SUBSTEP(0, true)  SUBSTEP(1, true)  SUBSTEP(2, true)  SUBSTEP(3, true)
        SUBSTEP(4, false) SUBSTEP(5, false) SUBSTEP(6, false) SUBSTEP(7, false)
        FLUSH(t)
    }
#undef GATE
#undef SUBSTEP
#undef FLUSH
    (void)outfl;
}

// ---------------------------------------------------------------------------
// Fallback (round-1 kernel) if ws_size can't hold gx
// ---------------------------------------------------------------------------
typedef float f32x2 __attribute__((ext_vector_type(2)));

__global__ __launch_bounds__(768) void gru_fused(
    const float* __restrict__ x, const float* __restrict__ W,
    const float* __restrict__ U, const float* __restrict__ b,
    float* __restrict__ out)
{
    const int bb  = blockIdx.x;
    const int tid = threadIdx.x;
    const int kh  = (tid >= G3) ? 1 : 0;
    const int c   = tid - kh * G3;
    const int kbase = kh * 64;

    f32x2 wcol[32], ucol[32];
    #pragma unroll
    for (int k2 = 0; k2 < 32; ++k2) {
        wcol[k2][0] = W[(size_t)(kbase + 2*k2 + 0) * G3 + c];
        wcol[k2][1] = W[(size_t)(kbase + 2*k2 + 1) * G3 + c];
        ucol[k2][0] = U[(size_t)(kbase + 2*k2 + 0) * G3 + c];
        ucol[k2][1] = U[(size_t)(kbase + 2*k2 + 1) * G3 + c];
    }
    const float bias = b[c];

    __shared__ float xs[2][DDIM];
    __shared__ float hs[DDIM];
    __shared__ float px[G3], ph[G3];
    __shared__ float rs[DDIM], ns[DDIM];

    if (tid < DDIM) { hs[tid] = 0.0f; xs[0][tid] = x[((size_t)bb * DDIM + tid) * TT]; }
    __syncthreads();

    const float* __restrict__ xrow = x   + (size_t)bb * DDIM * TT;
    float* __restrict__       orow = out + (size_t)bb * DDIM * TT;
    float zv = 0.0f;

    for (int t = 0; t < TT; ++t) {
        const float* xcur = xs[t & 1] + kbase;
        const float* hcur = hs + kbase;
        f32x2 axv = {0.f, 0.f}, ahv = {0.f, 0.f};
        #pragma unroll
        for (int k2 = 0; k2 < 32; ++k2) {
            f32x2 xv = *(const f32x2*)(xcur + 2*k2);
            f32x2 hv = *(const f32x2*)(hcur + 2*k2);
            axv += xv * wcol[k2];
            ahv += hv * ucol[k2];
        }
        float ax = axv[0] + axv[1];
        float ah = ahv[0] + ahv[1];
        if (kh) { px[c] = ax; ph[c] = ah; }
        if (t + 1 < TT && tid >= 128 && tid < 256) {
            const int k = tid - 128;
            xs[(t + 1) & 1][k] = xrow[(size_t)k * TT + (t + 1)];
        }
        __syncthreads();
        if (!kh) {
            ax += px[c]; ah += ph[c];
            if (c < DDIM)            zv = sigm_(ax + ah + bias);
            else if (c < 2*DDIM)     rs[c - DDIM] = sigm_(ax + ah + bias);
            else { px[c] = ax + bias; ph[c] = ah; }
        }
        __syncthreads();
        if (!kh && c >= 2*DDIM) {
            float r = rs[c - 2*DDIM];
            ns[c - 2*DDIM] = tanhf_(px[c] + r * ph[c]);
        }
        __syncthreads();
        if (tid < DDIM) {
            float n = ns[tid];
            float hnew = zv * hs[tid] + (1.0f - zv) * n;
            hs[tid] = hnew;
            orow[(size_t)tid * TT + t] = hnew;
        }
        __syncthreads();
    }
}

extern "C" void kernel_launch(void* const* d_in, const int* in_sizes, int n_in,
                              void* d_out, int out_size, void* d_ws, size_t ws_size,
                              hipStream_t stream) {
    const float* x = (const float*)d_in[0];
    const float* W = (const float*)d_in[1];
    const float* U = (const float*)d_in[2];
    const float* b = (const float*)d_in[3];
    float* out     = (float*)d_out;

    if (ws_size >= GX_BYTES) {
        unsigned short* gx = (unsigned short*)d_ws;
        hipLaunchKernelGGL(gx_gemm, dim3(16, 16), dim3(256), 0, stream, x, W, b, gx);
        hipLaunchKernelGGL(gru_rec, dim3(8), dim3(1024), 0, stream, gx, U, out);
    } else {
        hipLaunchKernelGGL(gru_fused, dim3(256), dim3(768), 0, stream, x, W, U, b, out);
    }
}

// Round 10
// 1686.180 us; speedup vs baseline: 1.8111x; 1.8111x over previous
//
#include <hip/hip_runtime.h>

typedef float f32x4 __attribute__((ext_vector_type(4)));
typedef short bf16x8 __attribute__((ext_vector_type(8)));

#define TT    2048
#define DDIM  128
#define G3    384
#define NBBLK 16
#define GXROW 6144   /* ushorts per t per batch-block */
#define GX_BYTES ((size_t)NBBLK * TT * GXROW * 2)  /* 402,653,184 B */

#define SCL_ZR (-1.4426950408889634f)
#define SCL_N  (-2.8853900817779268f)

__device__ __forceinline__ unsigned f2bf_u(float f) {
    unsigned u = __float_as_uint(f);
    return (u + 0x7FFFu + ((u >> 16) & 1u)) >> 16;   // RNE f32->bf16
}
__device__ __forceinline__ float bf_lo(unsigned u) { return __uint_as_float(u << 16); }
__device__ __forceinline__ float bf_hi(unsigned u) { return __uint_as_float(u & 0xffff0000u); }
__device__ __forceinline__ float rcp_(float x) { return __builtin_amdgcn_rcpf(x); }
__device__ __forceinline__ float exp2_(float x) {
    float d;
    asm("v_exp_f32 %0, %1" : "=v"(d) : "v"(x));   // register-only, safe
    return d;
}
__device__ __forceinline__ float sigm_(float v) { return rcp_(1.0f + exp2_(-1.4426950408889634f * v)); }
__device__ __forceinline__ float tanhf_(float v) { return 2.0f * rcp_(1.0f + exp2_(-2.8853900817779268f * v)) - 1.0f; }
__device__ __forceinline__ unsigned cvt_pk_bf16(float lo, float hi) {
    unsigned d;
    asm("v_cvt_pk_bf16_f32 %0, %1, %2" : "=v"(d) : "v"(lo), "v"(hi));
    return d;
}

// ---------------------------------------------------------------------------
// Kernel 1: gx^T = (x_t @ W + b)^T via swapped-operand MFMA.
// gx (ushort): [bblk][t][tile(24: 8z,8r,8n)][lk(4)][lc(16)][4], pre-scaled.
// ---------------------------------------------------------------------------
__global__ __launch_bounds__(256) void gx_gemm(
    const float* __restrict__ x, const float* __restrict__ W,
    const float* __restrict__ bias, unsigned short* __restrict__ gx)
{
    const int bblk  = blockIdx.x;
    const int ttile = blockIdx.y;
    const int tid = threadIdx.x;
    const int w  = tid >> 6;
    const int l  = tid & 63;
    const int lc = l & 15;
    const int lk = l >> 4;

    __shared__ unsigned short xs[16 * 16 * DDIM];   // [t16][r16][d128] bf16, swizzled

    const int tiles[6] = {2*w, 2*w+1, 2*w+8, 2*w+9, 2*w+16, 2*w+17};

    bf16x8 wfrag[6][4];
    f32x4  binit[6];
    #pragma unroll
    for (int i6 = 0; i6 < 6; ++i6) {
        const float scl = (i6 >= 4) ? SCL_N : SCL_ZR;
        #pragma unroll
        for (int i = 0; i < 4; ++i)
            binit[i6][i] = bias[tiles[i6] * 16 + lk * 4 + i] * scl;
        #pragma unroll
        for (int kt = 0; kt < 4; ++kt) {
            bf16x8 f;
            #pragma unroll
            for (int jj = 0; jj < 8; ++jj) {
                const int k = kt * 32 + lk * 8 + jj;
                f[jj] = (short)f2bf_u(W[k * G3 + tiles[i6] * 16 + lc] * scl);
            }
            wfrag[i6][kt] = f;
        }
    }

    int inoff[4];
    #pragma unroll
    for (int kt = 0; kt < 4; ++kt)
        inoff[kt] = (lc * 256 + kt * 64 + lk * 16) ^ ((lc & 7) << 4);

    const float* xb = x + (size_t)bblk * 16 * DDIM * TT;
    const int t0blk = ttile * 128;
    const int tq = tid & 3;
    const int pbase = tid >> 2;

    for (int chunk = 0; chunk < 8; ++chunk) {
        __syncthreads();
        const int t0 = t0blk + chunk * 16 + tq * 4;
        #pragma unroll 4
        for (int pp = 0; pp < 32; ++pp) {
            const int p = pbase + pp * 64;
            const int r = p >> 7, d = p & 127;
            f32x4 v = *(const f32x4*)(xb + (size_t)p * TT + t0);
            char* bp = (char*)xs + (tq * 4) * 4096 + (((r * 128 + d) * 2) ^ ((r & 7) << 4));
            const unsigned pkA = cvt_pk_bf16(v[0], v[1]);
            const unsigned pkB = cvt_pk_bf16(v[2], v[3]);
            *(unsigned short*)(bp)         = (unsigned short)pkA;
            *(unsigned short*)(bp + 4096)  = (unsigned short)(pkA >> 16);
            *(unsigned short*)(bp + 8192)  = (unsigned short)pkB;
            *(unsigned short*)(bp + 12288) = (unsigned short)(pkB >> 16);
        }
        __syncthreads();

        for (int t = 0; t < 16; ++t) {
            bf16x8 a[4];
            #pragma unroll
            for (int kt = 0; kt < 4; ++kt)
                a[kt] = *(const bf16x8*)((const char*)xs + t * 4096 + inoff[kt]);

            const int tglob = t0blk + chunk * 16 + t;
            #pragma unroll
            for (int i6 = 0; i6 < 6; ++i6) {
                f32x4 acc = binit[i6];
                #pragma unroll
                for (int kt = 0; kt < 4; ++kt)
                    acc = __builtin_amdgcn_mfma_f32_16x16x32_bf16(wfrag[i6][kt], a[kt], acc, 0, 0, 0);
                unsigned p0 = cvt_pk_bf16(acc[0], acc[1]);
                unsigned p1 = cvt_pk_bf16(acc[2], acc[3]);
                const size_t off = (size_t)(bblk * TT + tglob) * GXROW
                                   + (size_t)(((tiles[i6] * 4 + lk) * 16 + lc) * 4);
                *(uint2*)(gx + off) = make_uint2(p0, p1);
            }
        }
    }
}

// ---------------------------------------------------------------------------
// Kernel 2: sequential GRU recurrence, C^T form. 16 blocks x 512 threads.
// Round-7 structure verbatim; single delta: hlds staging store moved AFTER
// the barrier (r8-proven placement) to shorten the pre-barrier lgkm drain.
// ---------------------------------------------------------------------------
__global__ __launch_bounds__(512, 2) void gru_rec(
    const unsigned short* __restrict__ gx, const float* __restrict__ U,
    float* __restrict__ out)
{
    const int bblk = blockIdx.x;
    const int tid  = threadIdx.x;
    const int w  = tid >> 6;
    const int l  = tid & 63;
    const int lc = l & 15, lk = l >> 4;

    // A-operand: U^T fragments, pre-scaled
    bf16x8 uz[4], ur[4], un[4];
    #pragma unroll
    for (int kt = 0; kt < 4; ++kt) {
        bf16x8 fz, fr, fn;
        #pragma unroll
        for (int jj = 0; jj < 8; ++jj) {
            const int k = kt * 32 + lk * 8 + jj;
            fz[jj] = (short)f2bf_u(U[k * G3 + (w * 16 + lc)] * SCL_ZR);
            fr[jj] = (short)f2bf_u(U[k * G3 + 128 + (w * 16 + lc)] * SCL_ZR);
            fn[jj] = (short)f2bf_u(U[k * G3 + 256 + (w * 16 + lc)] * SCL_N);
        }
        uz[kt] = fz; ur[kt] = fr; un[kt] = fn;
    }

    __shared__ unsigned short hsA[2 * 2048];   // 8KB: 2 bufs x [b16][d128] bf16, swizzled
    __shared__ float hlds[16 * 16 * 128];      // 128KB out staging [t16][b16][d128], swizzled
    #pragma unroll
    for (int i = tid; i < 4096; i += 512) hsA[i] = 0;
    char* const hb_lds = (char*)hlds;

    // B-frag (h) read byte-offsets
    int roff[4];
    #pragma unroll
    for (int kt = 0; kt < 4; ++kt)
        roff[kt] = lc * 256 + ((kt * 64 + lk * 16) ^ (lc << 4));

    // h write: single b64 at row lc, d-cols w*16+lk*4..+3
    const int wb64 = lc * 256 + ((w * 32 + lk * 8) ^ (lc << 4));

    // hlds write: addr = hlv[J>>2] + (J&3)*8192 (imm)
    int hlv[4];
    {
        const int hlbase = lc * 512 + ((w * 64 + lk * 16) ^ ((lc & 7) << 4));
        #pragma unroll
        for (int s = 0; s < 4; ++s) hlv[s] = s * 32768 + (hlbase ^ (s << 6));
    }

    // flush: lane covers (d = dl, t-quad qfl); round r covers batch b = r
    const int dl  = w * 16 + (l >> 2);
    const int qfl = l & 3;
    const int flb = qfl * 32768 + ((dl * 4) ^ (qfl << 6));
    float* outl = out + ((size_t)bblk * 16 * DDIM + dl) * TT + qfl * 4;

    float hold[4] = {0.f, 0.f, 0.f, 0.f};

    const unsigned short* g0 = gx + (size_t)bblk * TT * GXROW
                               + (size_t)(((w * 4 + lk) * 16 + lc) * 4);

    // depth-4 gx prefetch ring
    uint2 rgz[4], rgr[4], rgn[4];
    #pragma unroll
    for (int d = 0; d < 4; ++d) {
        const unsigned short* gq = g0 + (size_t)d * GXROW;
        rgz[d] = *(const uint2*)(gq);
        rgr[d] = *(const uint2*)(gq + 2048);
        rgn[d] = *(const uint2*)(gq + 4096);
    }

    __syncthreads();

#define GATE(I)                                                               \
    {                                                                         \
        const float zz = rcp_(1.0f + exp2_(az_a[I] + az_b[I]));               \
        const float rr = rcp_(1.0f + exp2_(ar_a[I] + ar_b[I]));               \
        const float uu = gn##I + rr * (an_a[I] + an_b[I]);                    \
        const float nn = 2.0f * rcp_(1.0f + exp2_(uu)) - 1.0f;                \
        const float hn = nn + zz * (hold[I] - nn);                            \
        hold[I] = hn;                                                         \
        hh[I] = hn;                                                           \
    }

#define SUBSTEP(J, DOPF)                                                      \
    {                                                                         \
        const char* hb = (const char*)hsA + ((J) & 1) * 4096;                 \
        bf16x8 b0 = *(const bf16x8*)(hb + roff[0]);                           \
        bf16x8 b1 = *(const bf16x8*)(hb + roff[1]);                           \
        bf16x8 b2 = *(const bf16x8*)(hb + roff[2]);                           \
        bf16x8 b3 = *(const bf16x8*)(hb + roff[3]);                           \
        uint2 pz = rgz[(J) & 3], pr = rgr[(J) & 3], pn = rgn[(J) & 3];        \
        if (DOPF) {                                                           \
            const unsigned short* gq = gpt + (size_t)((J) + 4) * GXROW;       \
            rgz[(J) & 3] = *(const uint2*)(gq);                               \
            rgr[(J) & 3] = *(const uint2*)(gq + 2048);                        \
            rgn[(J) & 3] = *(const uint2*)(gq + 4096);                        \
        }                                                                     \
        f32x4 az_a, ar_a;                                                     \
        az_a[0] = bf_lo(pz.x); az_a[1] = bf_hi(pz.x);                         \
        az_a[2] = bf_lo(pz.y); az_a[3] = bf_hi(pz.y);                         \
        ar_a[0] = bf_lo(pr.x); ar_a[1] = bf_hi(pr.x);                         \
        ar_a[2] = bf_lo(pr.y); ar_a[3] = bf_hi(pr.y);                         \
        const float gn0 = bf_lo(pn.x), gn1 = bf_hi(pn.x);                     \
        const float gn2 = bf_lo(pn.y), gn3 = bf_hi(pn.y);                     \
        f32x4 an_a = (f32x4){0.f, 0.f, 0.f, 0.f};                             \
        f32x4 an_b = an_a, az_b = an_a, ar_b = an_a;                          \
        an_a = __builtin_amdgcn_mfma_f32_16x16x32_bf16(un[0], b0, an_a, 0, 0, 0); \
        an_b = __builtin_amdgcn_mfma_f32_16x16x32_bf16(un[2], b2, an_b, 0, 0, 0); \
        az_a = __builtin_amdgcn_mfma_f32_16x16x32_bf16(uz[0], b0, az_a, 0, 0, 0); \
        az_b = __builtin_amdgcn_mfma_f32_16x16x32_bf16(uz[2], b2, az_b, 0, 0, 0); \
        ar_a = __builtin_amdgcn_mfma_f32_16x16x32_bf16(ur[0], b0, ar_a, 0, 0, 0); \
        ar_b = __builtin_amdgcn_mfma_f32_16x16x32_bf16(ur[2], b2, ar_b, 0, 0, 0); \
        an_a = __builtin_amdgcn_mfma_f32_16x16x32_bf16(un[1], b1, an_a, 0, 0, 0); \
        an_b = __builtin_amdgcn_mfma_f32_16x16x32_bf16(un[3], b3, an_b, 0, 0, 0); \
        az_a = __builtin_amdgcn_mfma_f32_16x16x32_bf16(uz[1], b1, az_a, 0, 0, 0); \
        az_b = __builtin_amdgcn_mfma_f32_16x16x32_bf16(uz[3], b3, az_b, 0, 0, 0); \
        ar_a = __builtin_amdgcn_mfma_f32_16x16x32_bf16(ur[1], b1, ar_a, 0, 0, 0); \
        ar_b = __builtin_amdgcn_mfma_f32_16x16x32_bf16(ur[3], b3, ar_b, 0, 0, 0); \
        float hh[4];                                                          \
        GATE(0) GATE(1) GATE(2) GATE(3)                                       \
        {                                                                     \
            const unsigned pk01 = cvt_pk_bf16(hh[0], hh[1]);                  \
            const unsigned pk23 = cvt_pk_bf16(hh[2], hh[3]);                  \
            *(uint2*)((char*)hsA + ((((J) & 1) ^ 1) * 4096) + wb64)           \
                = make_uint2(pk01, pk23);                                     \
        }                                                                     \
        asm volatile("s_waitcnt lgkmcnt(0)" ::: "memory");                    \
        __builtin_amdgcn_s_barrier();                                         \
        /* out staging post-barrier (r8-proven): off the lgkm critical path */\
        *(f32x4*)(hb_lds + hlv[(J) >> 2] + ((J) & 3) * 8192)                  \
            = (f32x4){hh[0], hh[1], hh[2], hh[3]};                            \
    }

    // flush: own-wave data only -> lgkm drain, no barrier
#define FLUSH(T0)                                                             \
    asm volatile("s_waitcnt lgkmcnt(0)" ::: "memory");                        \
    _Pragma("unroll")                                                         \
    for (int r = 0; r < 16; ++r) {                                            \
        const int fr = (flb ^ ((r & 7) << 4)) + r * 512;                      \
        f32x4 v;                                                              \
        _Pragma("unroll")                                                     \
        for (int k = 0; k < 4; ++k)                                           \
            v[k] = *(const float*)(hb_lds + fr + k * 8192);                   \
        *(f32x4*)(outl + (size_t)r * (DDIM * TT) + (T0)) = v;                 \
    }

    for (int t = 0; t < TT - 16; t += 16) {
        const unsigned short* gpt = g0 + (size_t)t * GXROW;
        SUBSTEP(0, true)  SUBSTEP(1, true)  SUBSTEP(2, true)  SUBSTEP(3, true)
        SUBSTEP(4, true)  SUBSTEP(5, true)  SUBSTEP(6, true)  SUBSTEP(7, true)
        SUBSTEP(8, true)  SUBSTEP(9, true)  SUBSTEP(10, true) SUBSTEP(11, true)
        SUBSTEP(12, true) SUBSTEP(13, true) SUBSTEP(14, true) SUBSTEP(15, true)
        FLUSH(t)
    }
    {
        const int t = TT - 16;
        const unsigned short* gpt = g0 + (size_t)t * GXROW;
        SUBSTEP(0, true)  SUBSTEP(1, true)  SUBSTEP(2, true)  SUBSTEP(3, true)
        SUBSTEP(4, true)  SUBSTEP(5, true)  SUBSTEP(6, true)  SUBSTEP(7, true)
        SUBSTEP(8, true)  SUBSTEP(9, true)  SUBSTEP(10, true) SUBSTEP(11, true)
        SUBSTEP(12, false) SUBSTEP(13, false) SUBSTEP(14, false) SUBSTEP(15, false)
        FLUSH(t)
    }
#undef GATE
#undef SUBSTEP
#undef FLUSH
}

// ---------------------------------------------------------------------------
// Fallback (round-1 kernel) if ws_size can't hold gx
// ---------------------------------------------------------------------------
typedef float f32x2 __attribute__((ext_vector_type(2)));

__global__ __launch_bounds__(768) void gru_fused(
    const float* __restrict__ x, const float* __restrict__ W,
    const float* __restrict__ U, const float* __restrict__ b,
    float* __restrict__ out)
{
    const int bb  = blockIdx.x;
    const int tid = threadIdx.x;
    const int kh  = (tid >= G3) ? 1 : 0;
    const int c   = tid - kh * G3;
    const int kbase = kh * 64;

    f32x2 wcol[32], ucol[32];
    #pragma unroll
    for (int k2 = 0; k2 < 32; ++k2) {
        wcol[k2][0] = W[(size_t)(kbase + 2*k2 + 0) * G3 + c];
        wcol[k2][1] = W[(size_t)(kbase + 2*k2 + 1) * G3 + c];
        ucol[k2][0] = U[(size_t)(kbase + 2*k2 + 0) * G3 + c];
        ucol[k2][1] = U[(size_t)(kbase + 2*k2 + 1) * G3 + c];
    }
    const float bias = b[c];

    __shared__ float xs[2][DDIM];
    __shared__ float hs[DDIM];
    __shared__ float px[G3], ph[G3];
    __shared__ float rs[DDIM], ns[DDIM];

    if (tid < DDIM) { hs[tid] = 0.0f; xs[0][tid] = x[((size_t)bb * DDIM + tid) * TT]; }
    __syncthreads();

    const float* __restrict__ xrow = x   + (size_t)bb * DDIM * TT;
    float* __restrict__       orow = out + (size_t)bb * DDIM * TT;
    float zv = 0.0f;

    for (int t = 0; t < TT; ++t) {
        const float* xcur = xs[t & 1] + kbase;
        const float* hcur = hs + kbase;
        f32x2 axv = {0.f, 0.f}, ahv = {0.f, 0.f};
        #pragma unroll
        for (int k2 = 0; k2 < 32; ++k2) {
            f32x2 xv = *(const f32x2*)(xcur + 2*k2);
            f32x2 hv = *(const f32x2*)(hcur + 2*k2);
            axv += xv * wcol[k2];
            ahv += hv * ucol[k2];
        }
        float ax = axv[0] + axv[1];
        float ah = ahv[0] + ahv[1];
        if (kh) { px[c] = ax; ph[c] = ah; }
        if (t + 1 < TT && tid >= 128 && tid < 256) {
            const int k = tid - 128;
            xs[(t + 1) & 1][k] = xrow[(size_t)k * TT + (t + 1)];
        }
        __syncthreads();
        if (!kh) {
            ax += px[c]; ah += ph[c];
            if (c < DDIM)            zv = sigm_(ax + ah + bias);
            else if (c < 2*DDIM)     rs[c - DDIM] = sigm_(ax + ah + bias);
            else { px[c] = ax + bias; ph[c] = ah; }
        }
        __syncthreads();
        if (!kh && c >= 2*DDIM) {
            float r = rs[c - 2*DDIM];
            ns[c - 2*DDIM] = tanhf_(px[c] + r * ph[c]);
        }
        __syncthreads();
        if (tid < DDIM) {
            float n = ns[tid];
            float hnew = zv * hs[tid] + (1.0f - zv) * n;
            hs[tid] = hnew;
            orow[(size_t)tid * TT + t] = hnew;
        }
        __syncthreads();
    }
}

extern "C" void kernel_launch(void* const* d_in, const int* in_sizes, int n_in,
                              void* d_out, int out_size, void* d_ws, size_t ws_size,
                              hipStream_t stream) {
    const float* x = (const float*)d_in[0];
    const float* W = (const float*)d_in[1];
    const float* U = (const float*)d_in[2];
    const float* b = (const float*)d_in[3];
    float* out     = (float*)d_out;

    if (ws_size >= GX_BYTES) {
        unsigned short* gx = (unsigned short*)d_ws;
        hipLaunchKernelGGL(gx_gemm, dim3(16, 16), dim3(256), 0, stream, x, W, b, gx);
        hipLaunchKernelGGL(gru_rec, dim3(16), dim3(512), 0, stream, gx, U, out);
    } else {
        hipLaunchKernelGGL(gru_fused, dim3(256), dim3(768), 0, stream, x, W, U, b, out);
    }
}